// Round 3
// baseline (222.567 us; speedup 1.0000x reference)
//
#include <hip/hip_runtime.h>

#define NEAR0f 1e-8f
#define REGf   0.002f

typedef float __attribute__((ext_vector_type(4))) f32x4;
typedef int   __attribute__((ext_vector_type(4))) i32x4;

__device__ __forceinline__ float wave_reduce(float v) {
#pragma unroll
    for (int off = 32; off > 0; off >>= 1)
        v += __shfl_down(v, off, 64);
    return v;
}

// sum of log(selected prob) over 4 elements, tree-summed
__device__ __forceinline__ float nll4(f32x4 p, i32x4 l) {
    float a0 = l.x ? p.x : 1.0f - p.x;
    float a1 = l.y ? p.y : 1.0f - p.y;
    float a2 = l.z ? p.z : 1.0f - p.z;
    float a3 = l.w ? p.w : 1.0f - p.w;
    float g0 = __logf(fmaxf(a0, NEAR0f)) + __logf(fmaxf(a1, NEAR0f));
    float g1 = __logf(fmaxf(a2, NEAR0f)) + __logf(fmaxf(a3, NEAR0f));
    return g0 + g1;
}

__device__ __forceinline__ float sq4(f32x4 a, float acc) {
    return fmaf(a.x, a.x, fmaf(a.y, a.y, fmaf(a.z, a.z, fmaf(a.w, a.w, acc))));
}

// Fused pass: NLL terms + sum(W1^2) + sum(W2^2).
// Concurrency = waves/CU x loads-in-flight: 8 blocks/CU (launch_bounds 256,8
// pins 32 waves/CU) x 8x16B outstanding loads per thread.
__global__ __launch_bounds__(256, 8) void reduce_all(
    const f32x4* __restrict__ p4,
    const i32x4* __restrict__ l4,
    const f32x4* __restrict__ w1,
    const f32x4* __restrict__ w2,
    float* __restrict__ acc,
    int n4, int w4)
{
    const int tid    = blockIdx.x * blockDim.x + threadIdx.x;
    const int stride = gridDim.x * blockDim.x;

    float nll0 = 0.0f, nll1 = 0.0f, nll2 = 0.0f, nll3 = 0.0f;
    int i = tid;
    for (; i + 3 * stride < n4; i += 4 * stride) {
        f32x4 p0 = p4[i];
        f32x4 p1 = p4[i + stride];
        f32x4 p2 = p4[i + 2 * stride];
        f32x4 p3 = p4[i + 3 * stride];
        i32x4 l0 = l4[i];
        i32x4 l1 = l4[i + stride];
        i32x4 l2 = l4[i + 2 * stride];
        i32x4 l3 = l4[i + 3 * stride];
        nll0 -= nll4(p0, l0);
        nll1 -= nll4(p1, l1);
        nll2 -= nll4(p2, l2);
        nll3 -= nll4(p3, l3);
    }
    for (; i < n4; i += stride) {
        nll0 -= nll4(p4[i], l4[i]);
    }
    float nll = (nll0 + nll1) + (nll2 + nll3);

    float s1a = 0.0f, s1b = 0.0f, s2a = 0.0f, s2b = 0.0f;
    int j = tid;
    for (; j + 3 * stride < w4; j += 4 * stride) {
        f32x4 a0 = w1[j];
        f32x4 a1 = w1[j + stride];
        f32x4 a2 = w1[j + 2 * stride];
        f32x4 a3 = w1[j + 3 * stride];
        f32x4 b0 = w2[j];
        f32x4 b1 = w2[j + stride];
        f32x4 b2 = w2[j + 2 * stride];
        f32x4 b3 = w2[j + 3 * stride];
        s1a = sq4(a0, s1a); s1b = sq4(a1, s1b);
        s1a = sq4(a2, s1a); s1b = sq4(a3, s1b);
        s2a = sq4(b0, s2a); s2b = sq4(b1, s2b);
        s2a = sq4(b2, s2a); s2b = sq4(b3, s2b);
    }
    for (; j < w4; j += stride) {
        s1a = sq4(w1[j], s1a);
        s2a = sq4(w2[j], s2a);
    }
    float s1 = s1a + s1b;
    float s2 = s2a + s2b;

    nll = wave_reduce(nll);
    s1  = wave_reduce(s1);
    s2  = wave_reduce(s2);

    __shared__ float sm[3][4];
    const int lane = threadIdx.x & 63;
    const int wave = threadIdx.x >> 6;
    if (lane == 0) { sm[0][wave] = nll; sm[1][wave] = s1; sm[2][wave] = s2; }
    __syncthreads();
    if (threadIdx.x == 0) {
        atomicAdd(&acc[0], sm[0][0] + sm[0][1] + sm[0][2] + sm[0][3]);
        atomicAdd(&acc[1], sm[1][0] + sm[1][1] + sm[1][2] + sm[1][3]);
        atomicAdd(&acc[2], sm[2][0] + sm[2][1] + sm[2][2] + sm[2][3]);
    }
}

// d_ws is poisoned 0xAA before every launch — zero accumulators ourselves.
__global__ void init_acc(float* acc) {
    acc[0] = 0.0f; acc[1] = 0.0f; acc[2] = 0.0f;
}

__global__ void finalize(const float* __restrict__ acc, float* __restrict__ out,
                         float invN) {
    out[0] = acc[0] * invN + REGf * (sqrtf(acc[1]) + sqrtf(acc[2]));
}

extern "C" void kernel_launch(void* const* d_in, const int* in_sizes, int n_in,
                              void* d_out, int out_size, void* d_ws, size_t ws_size,
                              hipStream_t stream) {
    const float* out1  = (const float*)d_in[0];   // [N,1] fp32
    const int*   label = (const int*)d_in[1];     // [N] int32
    const float* W1    = (const float*)d_in[2];   // [1024,4096] fp32
    const float* W2    = (const float*)d_in[3];   // [4096,1024] fp32

    const int N  = in_sizes[0];
    const int n4 = N / 4;
    const int w4 = in_sizes[2] / 4;               // W1 and W2 same size

    float* acc = (float*)d_ws;

    init_acc<<<1, 1, 0, stream>>>(acc);
    // 2048 blocks x 256 = 8 blocks/CU resident (VGPR<=64 via launch_bounds):
    // N-loop = 8 iters/thread (2 unrolled batches), W-loop = 2 iters/thread.
    reduce_all<<<2048, 256, 0, stream>>>(
        (const f32x4*)out1, (const i32x4*)label,
        (const f32x4*)W1,   (const f32x4*)W2,
        acc, n4, w4);
    finalize<<<1, 1, 0, stream>>>(acc, (float*)d_out, 1.0f / (float)N);
}

// Round 4
// 221.936 us; speedup vs baseline: 1.0028x; 1.0028x over previous
//
#include <hip/hip_runtime.h>

#define NEAR0f 1e-8f
#define REGf   0.002f

typedef float __attribute__((ext_vector_type(4))) f32x4;
typedef int   __attribute__((ext_vector_type(4))) i32x4;

__device__ __forceinline__ f32x4 ntload(const f32x4* p) { return __builtin_nontemporal_load(p); }
__device__ __forceinline__ i32x4 ntload(const i32x4* p) { return __builtin_nontemporal_load(p); }

__device__ __forceinline__ float wave_reduce(float v) {
#pragma unroll
    for (int off = 32; off > 0; off >>= 1)
        v += __shfl_down(v, off, 64);
    return v;
}

// sum of log(selected prob) over 4 elements, tree-summed
__device__ __forceinline__ float nll4(f32x4 p, i32x4 l) {
    float a0 = l.x ? p.x : 1.0f - p.x;
    float a1 = l.y ? p.y : 1.0f - p.y;
    float a2 = l.z ? p.z : 1.0f - p.z;
    float a3 = l.w ? p.w : 1.0f - p.w;
    float g0 = __logf(fmaxf(a0, NEAR0f)) + __logf(fmaxf(a1, NEAR0f));
    float g1 = __logf(fmaxf(a2, NEAR0f)) + __logf(fmaxf(a3, NEAR0f));
    return g0 + g1;
}

__device__ __forceinline__ float sq4(f32x4 a, float acc) {
    return fmaf(a.x, a.x, fmaf(a.y, a.y, fmaf(a.z, a.z, fmaf(a.w, a.w, acc))));
}

// Fused pass: NLL terms + sum(W1^2) + sum(W2^2).
// Nontemporal loads (bypass L2 allocation — harness's 160MB input-restore
// leaves dirty lines; normal loads force writeback evictions, R2 vs R3
// evidence = 1.63x). 8 blocks/CU + 8x16B loads in flight per thread.
__global__ __launch_bounds__(256, 8) void reduce_all(
    const f32x4* __restrict__ p4,
    const i32x4* __restrict__ l4,
    const f32x4* __restrict__ w1,
    const f32x4* __restrict__ w2,
    float* __restrict__ acc,
    int n4, int w4)
{
    const int tid    = blockIdx.x * blockDim.x + threadIdx.x;
    const int stride = gridDim.x * blockDim.x;

    float nll0 = 0.0f, nll1 = 0.0f, nll2 = 0.0f, nll3 = 0.0f;
    int i = tid;
    for (; i + 3 * stride < n4; i += 4 * stride) {
        f32x4 p0 = ntload(p4 + i);
        f32x4 p1 = ntload(p4 + i + stride);
        f32x4 p2 = ntload(p4 + i + 2 * stride);
        f32x4 p3 = ntload(p4 + i + 3 * stride);
        i32x4 l0 = ntload(l4 + i);
        i32x4 l1 = ntload(l4 + i + stride);
        i32x4 l2 = ntload(l4 + i + 2 * stride);
        i32x4 l3 = ntload(l4 + i + 3 * stride);
        nll0 -= nll4(p0, l0);
        nll1 -= nll4(p1, l1);
        nll2 -= nll4(p2, l2);
        nll3 -= nll4(p3, l3);
    }
    for (; i + stride < n4; i += 2 * stride) {
        f32x4 p0 = ntload(p4 + i);
        f32x4 p1 = ntload(p4 + i + stride);
        i32x4 l0 = ntload(l4 + i);
        i32x4 l1 = ntload(l4 + i + stride);
        nll0 -= nll4(p0, l0);
        nll1 -= nll4(p1, l1);
    }
    for (; i < n4; i += stride) {
        nll0 -= nll4(ntload(p4 + i), ntload(l4 + i));
    }
    float nll = (nll0 + nll1) + (nll2 + nll3);

    float s1a = 0.0f, s1b = 0.0f, s2a = 0.0f, s2b = 0.0f;
    int j = tid;
    for (; j + 3 * stride < w4; j += 4 * stride) {
        f32x4 a0 = ntload(w1 + j);
        f32x4 a1 = ntload(w1 + j + stride);
        f32x4 a2 = ntload(w1 + j + 2 * stride);
        f32x4 a3 = ntload(w1 + j + 3 * stride);
        f32x4 b0 = ntload(w2 + j);
        f32x4 b1 = ntload(w2 + j + stride);
        f32x4 b2 = ntload(w2 + j + 2 * stride);
        f32x4 b3 = ntload(w2 + j + 3 * stride);
        s1a = sq4(a0, s1a); s1b = sq4(a1, s1b);
        s1a = sq4(a2, s1a); s1b = sq4(a3, s1b);
        s2a = sq4(b0, s2a); s2b = sq4(b1, s2b);
        s2a = sq4(b2, s2a); s2b = sq4(b3, s2b);
    }
    for (; j + stride < w4; j += 2 * stride) {     // 2x tier: active at 2048 blocks
        f32x4 a0 = ntload(w1 + j);
        f32x4 a1 = ntload(w1 + j + stride);
        f32x4 b0 = ntload(w2 + j);
        f32x4 b1 = ntload(w2 + j + stride);
        s1a = sq4(a0, s1a); s1b = sq4(a1, s1b);
        s2a = sq4(b0, s2a); s2b = sq4(b1, s2b);
    }
    for (; j < w4; j += stride) {
        s1a = sq4(ntload(w1 + j), s1a);
        s2a = sq4(ntload(w2 + j), s2a);
    }
    float s1 = s1a + s1b;
    float s2 = s2a + s2b;

    nll = wave_reduce(nll);
    s1  = wave_reduce(s1);
    s2  = wave_reduce(s2);

    __shared__ float sm[3][4];
    const int lane = threadIdx.x & 63;
    const int wave = threadIdx.x >> 6;
    if (lane == 0) { sm[0][wave] = nll; sm[1][wave] = s1; sm[2][wave] = s2; }
    __syncthreads();
    if (threadIdx.x == 0) {
        atomicAdd(&acc[0], sm[0][0] + sm[0][1] + sm[0][2] + sm[0][3]);
        atomicAdd(&acc[1], sm[1][0] + sm[1][1] + sm[1][2] + sm[1][3]);
        atomicAdd(&acc[2], sm[2][0] + sm[2][1] + sm[2][2] + sm[2][3]);
    }
}

// d_ws is poisoned 0xAA before every launch — zero accumulators ourselves.
__global__ void init_acc(float* acc) {
    acc[0] = 0.0f; acc[1] = 0.0f; acc[2] = 0.0f;
}

__global__ void finalize(const float* __restrict__ acc, float* __restrict__ out,
                         float invN) {
    out[0] = acc[0] * invN + REGf * (sqrtf(acc[1]) + sqrtf(acc[2]));
}

extern "C" void kernel_launch(void* const* d_in, const int* in_sizes, int n_in,
                              void* d_out, int out_size, void* d_ws, size_t ws_size,
                              hipStream_t stream) {
    const float* out1  = (const float*)d_in[0];   // [N,1] fp32
    const int*   label = (const int*)d_in[1];     // [N] int32
    const float* W1    = (const float*)d_in[2];   // [1024,4096] fp32
    const float* W2    = (const float*)d_in[3];   // [4096,1024] fp32

    const int N  = in_sizes[0];
    const int n4 = N / 4;
    const int w4 = in_sizes[2] / 4;               // W1 and W2 same size

    float* acc = (float*)d_ws;

    init_acc<<<1, 1, 0, stream>>>(acc);
    // 2048 blocks x 256 = 8 blocks/CU resident: N-loop = 2 unrolled 4x batches,
    // W-loop = one 2x batch per thread.
    reduce_all<<<2048, 256, 0, stream>>>(
        (const f32x4*)out1, (const i32x4*)label,
        (const f32x4*)W1,   (const f32x4*)W2,
        acc, n4, w4);
    finalize<<<1, 1, 0, stream>>>(acc, (float*)d_out, 1.0f / (float)N);
}

// Round 5
// 194.242 us; speedup vs baseline: 1.1458x; 1.1426x over previous
//
#include <hip/hip_runtime.h>

#define NEAR0f 1e-8f
#define REGf   0.002f

typedef float __attribute__((ext_vector_type(4))) f32x4;
typedef int   __attribute__((ext_vector_type(4))) i32x4;

__device__ __forceinline__ f32x4 ntload(const f32x4* p) { return __builtin_nontemporal_load(p); }
__device__ __forceinline__ i32x4 ntload(const i32x4* p) { return __builtin_nontemporal_load(p); }

__device__ __forceinline__ float wave_reduce(float v) {
#pragma unroll
    for (int off = 32; off > 0; off >>= 1)
        v += __shfl_down(v, off, 64);
    return v;
}

// sum of log(selected prob) over 4 elements, tree-summed
__device__ __forceinline__ float nll4(f32x4 p, i32x4 l) {
    float a0 = l.x ? p.x : 1.0f - p.x;
    float a1 = l.y ? p.y : 1.0f - p.y;
    float a2 = l.z ? p.z : 1.0f - p.z;
    float a3 = l.w ? p.w : 1.0f - p.w;
    float g0 = __logf(fmaxf(a0, NEAR0f)) + __logf(fmaxf(a1, NEAR0f));
    float g1 = __logf(fmaxf(a2, NEAR0f)) + __logf(fmaxf(a3, NEAR0f));
    return g0 + g1;
}

__device__ __forceinline__ float sq4(f32x4 a, float acc) {
    return fmaf(a.x, a.x, fmaf(a.y, a.y, fmaf(a.z, a.z, fmaf(a.w, a.w, acc))));
}

// Fused pass: NLL terms + sum(W1^2) + sum(W2^2).
// Perf tracks in-flight loads per wave (R1 VGPR12=122us, R4 VGPR24=100us,
// R2 VGPR32=63us). launch_bounds(256,2) unlocks up to 256 VGPRs so the
// 16-load batch (64 VGPRs payload) is NOT serialized by the allocator.
__global__ __launch_bounds__(256, 2) void reduce_all(
    const f32x4* __restrict__ p4,
    const i32x4* __restrict__ l4,
    const f32x4* __restrict__ w1,
    const f32x4* __restrict__ w2,
    float* __restrict__ acc,
    int n4, int w4)
{
    const int tid    = blockIdx.x * blockDim.x + threadIdx.x;
    const int stride = gridDim.x * blockDim.x;

    float na[8] = {0, 0, 0, 0, 0, 0, 0, 0};
    int i = tid;
    for (; i + 7 * stride < n4; i += 8 * stride) {   // 16 loads in flight
        f32x4 p[8];
        i32x4 l[8];
#pragma unroll
        for (int u = 0; u < 8; ++u) p[u] = ntload(p4 + i + u * stride);
#pragma unroll
        for (int u = 0; u < 8; ++u) l[u] = ntload(l4 + i + u * stride);
#pragma unroll
        for (int u = 0; u < 8; ++u) na[u] -= nll4(p[u], l[u]);
    }
    for (; i < n4; i += stride) {
        na[0] -= nll4(ntload(p4 + i), ntload(l4 + i));
    }
    float nll = ((na[0] + na[1]) + (na[2] + na[3]))
              + ((na[4] + na[5]) + (na[6] + na[7]));

    float s1v[4] = {0, 0, 0, 0}, s2v[4] = {0, 0, 0, 0};
    int j = tid;
    for (; j + 3 * stride < w4; j += 4 * stride) {   // 8 loads in flight
        f32x4 a[4], b[4];
#pragma unroll
        for (int u = 0; u < 4; ++u) a[u] = ntload(w1 + j + u * stride);
#pragma unroll
        for (int u = 0; u < 4; ++u) b[u] = ntload(w2 + j + u * stride);
#pragma unroll
        for (int u = 0; u < 4; ++u) {
            s1v[u] = sq4(a[u], s1v[u]);
            s2v[u] = sq4(b[u], s2v[u]);
        }
    }
    for (; j < w4; j += stride) {
        s1v[0] = sq4(ntload(w1 + j), s1v[0]);
        s2v[0] = sq4(ntload(w2 + j), s2v[0]);
    }
    float s1 = (s1v[0] + s1v[1]) + (s1v[2] + s1v[3]);
    float s2 = (s2v[0] + s2v[1]) + (s2v[2] + s2v[3]);

    nll = wave_reduce(nll);
    s1  = wave_reduce(s1);
    s2  = wave_reduce(s2);

    __shared__ float sm[3][4];
    const int lane = threadIdx.x & 63;
    const int wave = threadIdx.x >> 6;
    if (lane == 0) { sm[0][wave] = nll; sm[1][wave] = s1; sm[2][wave] = s2; }
    __syncthreads();
    if (threadIdx.x == 0) {
        atomicAdd(&acc[0], sm[0][0] + sm[0][1] + sm[0][2] + sm[0][3]);
        atomicAdd(&acc[1], sm[1][0] + sm[1][1] + sm[1][2] + sm[1][3]);
        atomicAdd(&acc[2], sm[2][0] + sm[2][1] + sm[2][2] + sm[2][3]);
    }
}

// d_ws is poisoned 0xAA before every launch — zero accumulators ourselves.
__global__ void init_acc(float* acc) {
    acc[0] = 0.0f; acc[1] = 0.0f; acc[2] = 0.0f;
}

__global__ void finalize(const float* __restrict__ acc, float* __restrict__ out,
                         float invN) {
    out[0] = acc[0] * invN + REGf * (sqrtf(acc[1]) + sqrtf(acc[2]));
}

extern "C" void kernel_launch(void* const* d_in, const int* in_sizes, int n_in,
                              void* d_out, int out_size, void* d_ws, size_t ws_size,
                              hipStream_t stream) {
    const float* out1  = (const float*)d_in[0];   // [N,1] fp32
    const int*   label = (const int*)d_in[1];     // [N] int32
    const float* W1    = (const float*)d_in[2];   // [1024,4096] fp32
    const float* W2    = (const float*)d_in[3];   // [4096,1024] fp32

    const int N  = in_sizes[0];
    const int n4 = N / 4;
    const int w4 = in_sizes[2] / 4;               // W1 and W2 same size

    float* acc = (float*)d_ws;

    init_acc<<<1, 1, 0, stream>>>(acc);
    // 1024 blocks x 256 (R2's best grid): N-loop = exactly 2 batches of 8,
    // W-loop = exactly 1 batch of 4 per thread.
    reduce_all<<<1024, 256, 0, stream>>>(
        (const f32x4*)out1, (const i32x4*)label,
        (const f32x4*)W1,   (const f32x4*)W2,
        acc, n4, w4);
    finalize<<<1, 1, 0, stream>>>(acc, (float*)d_out, 1.0f / (float)N);
}

// Round 6
// 191.670 us; speedup vs baseline: 1.1612x; 1.0134x over previous
//
#include <hip/hip_runtime.h>

#define NEAR0f 1e-8f
#define REGf   0.002f

typedef float __attribute__((ext_vector_type(4))) f32x4;
typedef int   __attribute__((ext_vector_type(4))) i32x4;

#if defined(__has_builtin)
#if __has_builtin(__builtin_amdgcn_sched_barrier)
#define SCHED_FENCE() __builtin_amdgcn_sched_barrier(0)
#endif
#endif
#ifndef SCHED_FENCE
#define SCHED_FENCE()
#endif

__device__ __forceinline__ f32x4 ntload(const f32x4* p) { return __builtin_nontemporal_load(p); }
__device__ __forceinline__ i32x4 ntload(const i32x4* p) { return __builtin_nontemporal_load(p); }

__device__ __forceinline__ float wave_reduce(float v) {
#pragma unroll
    for (int off = 32; off > 0; off >>= 1)
        v += __shfl_down(v, off, 64);
    return v;
}

// sum of log(selected prob) over 4 elements, tree-summed
__device__ __forceinline__ float nll4(f32x4 p, i32x4 l) {
    float a0 = l.x ? p.x : 1.0f - p.x;
    float a1 = l.y ? p.y : 1.0f - p.y;
    float a2 = l.z ? p.z : 1.0f - p.z;
    float a3 = l.w ? p.w : 1.0f - p.w;
    float g0 = __logf(fmaxf(a0, NEAR0f)) + __logf(fmaxf(a1, NEAR0f));
    float g1 = __logf(fmaxf(a2, NEAR0f)) + __logf(fmaxf(a3, NEAR0f));
    return g0 + g1;
}

__device__ __forceinline__ float sq4(f32x4 a, float acc) {
    return fmaf(a.x, a.x, fmaf(a.y, a.y, fmaf(a.z, a.z, fmaf(a.w, a.w, acc))));
}

// Fused pass: NLL terms + sum(W1^2) + sum(W2^2).
// R5 lesson: pragma-unroll batches get re-serialized by the pressure-aware
// scheduler (VGPR stuck at 32). sched_barrier(0) between the load group and
// the consume group FORCES all 16 loads to stay outstanding together.
__global__ __launch_bounds__(256, 2) void reduce_all(
    const f32x4* __restrict__ p4,
    const i32x4* __restrict__ l4,
    const f32x4* __restrict__ w1,
    const f32x4* __restrict__ w2,
    float* __restrict__ acc,
    int n4, int w4)
{
    const int tid    = blockIdx.x * blockDim.x + threadIdx.x;
    const int stride = gridDim.x * blockDim.x;

    float na[8] = {0, 0, 0, 0, 0, 0, 0, 0};
    int i = tid;
    for (; i + 7 * stride < n4; i += 8 * stride) {   // 16 loads in flight
        f32x4 p[8];
        i32x4 l[8];
#pragma unroll
        for (int u = 0; u < 8; ++u) p[u] = ntload(p4 + i + u * stride);
#pragma unroll
        for (int u = 0; u < 8; ++u) l[u] = ntload(l4 + i + u * stride);
        SCHED_FENCE();                               // loads may not sink past here
#pragma unroll
        for (int u = 0; u < 8; ++u) na[u] -= nll4(p[u], l[u]);
    }
    for (; i < n4; i += stride) {
        na[0] -= nll4(ntload(p4 + i), ntload(l4 + i));
    }
    float nll = ((na[0] + na[1]) + (na[2] + na[3]))
              + ((na[4] + na[5]) + (na[6] + na[7]));

    float s1v[4] = {0, 0, 0, 0}, s2v[4] = {0, 0, 0, 0};
    int j = tid;
    for (; j + 3 * stride < w4; j += 4 * stride) {   // 8 loads in flight
        f32x4 a[4], b[4];
#pragma unroll
        for (int u = 0; u < 4; ++u) a[u] = ntload(w1 + j + u * stride);
#pragma unroll
        for (int u = 0; u < 4; ++u) b[u] = ntload(w2 + j + u * stride);
        SCHED_FENCE();
#pragma unroll
        for (int u = 0; u < 4; ++u) {
            s1v[u] = sq4(a[u], s1v[u]);
            s2v[u] = sq4(b[u], s2v[u]);
        }
    }
    for (; j < w4; j += stride) {
        s1v[0] = sq4(ntload(w1 + j), s1v[0]);
        s2v[0] = sq4(ntload(w2 + j), s2v[0]);
    }
    float s1 = (s1v[0] + s1v[1]) + (s1v[2] + s1v[3]);
    float s2 = (s2v[0] + s2v[1]) + (s2v[2] + s2v[3]);

    nll = wave_reduce(nll);
    s1  = wave_reduce(s1);
    s2  = wave_reduce(s2);

    __shared__ float sm[3][4];
    const int lane = threadIdx.x & 63;
    const int wave = threadIdx.x >> 6;
    if (lane == 0) { sm[0][wave] = nll; sm[1][wave] = s1; sm[2][wave] = s2; }
    __syncthreads();
    if (threadIdx.x == 0) {
        atomicAdd(&acc[0], sm[0][0] + sm[0][1] + sm[0][2] + sm[0][3]);
        atomicAdd(&acc[1], sm[1][0] + sm[1][1] + sm[1][2] + sm[1][3]);
        atomicAdd(&acc[2], sm[2][0] + sm[2][1] + sm[2][2] + sm[2][3]);
    }
}

// d_ws is poisoned 0xAA before every launch — zero accumulators ourselves.
__global__ void init_acc(float* acc) {
    acc[0] = 0.0f; acc[1] = 0.0f; acc[2] = 0.0f;
}

__global__ void finalize(const float* __restrict__ acc, float* __restrict__ out,
                         float invN) {
    out[0] = acc[0] * invN + REGf * (sqrtf(acc[1]) + sqrtf(acc[2]));
}

extern "C" void kernel_launch(void* const* d_in, const int* in_sizes, int n_in,
                              void* d_out, int out_size, void* d_ws, size_t ws_size,
                              hipStream_t stream) {
    const float* out1  = (const float*)d_in[0];   // [N,1] fp32
    const int*   label = (const int*)d_in[1];     // [N] int32
    const float* W1    = (const float*)d_in[2];   // [1024,4096] fp32
    const float* W2    = (const float*)d_in[3];   // [4096,1024] fp32

    const int N  = in_sizes[0];
    const int n4 = N / 4;
    const int w4 = in_sizes[2] / 4;               // W1 and W2 same size

    float* acc = (float*)d_ws;

    init_acc<<<1, 1, 0, stream>>>(acc);
    // 1024 blocks x 256 (best known grid): N-loop = exactly 2 batches of 8,
    // W-loop = exactly 1 batch of 4 per thread.
    reduce_all<<<1024, 256, 0, stream>>>(
        (const f32x4*)out1, (const i32x4*)label,
        (const f32x4*)W1,   (const f32x4*)W2,
        acc, n4, w4);
    finalize<<<1, 1, 0, stream>>>(acc, (float*)d_out, 1.0f / (float)N);
}